// Round 6
// baseline (327.999 us; speedup 1.0000x reference)
//
#include <hip/hip_runtime.h>
#include <math.h>

// Attention: out = softmax((q@Wq+bq)(k@Wk+bk)^T / sqrt(D)) @ (v@Wv+bv)
// B=4, S=2048, D=1024, fp32 in/out.
//
// Round 12: faithful m201-style 256^2 4-phase GEMM + coalesced LDS epilogue.
// r11 post-mortem: +32MB WRITE in r7/r11 (per-wave M=128) vs clean r8-r10
// (M=64) = C-write amplification from 2B scalar stores over a 128-row wave
// footprint, NOT spill (acc in AGPRs). Geometry helped scores/pv despite it.
// This round:
//  - 256x256 tile, 8 waves (2Mx4N), per-wave 128x64, acc[8][4], BK=64
//  - LDS 128KB: 2 bufs x {A0,A1,B0,B1} K-slice regions [256][32] (16KB each)
//  - 4 phases/K-tile, 16 MFMA each; per phase: {8|4 ds_read; 1 half-tile
//    stage (2 gload_lds); SBAR; lgkm(0); setprio1; MFMA16; setprio0;
//    [VMW]; SBAR}  -- consumption order == issue order (A0,B0,A1,B1)
//  - counted vmcnt(4) twice per K-tile, 3-phase issue-to-guard distance:
//      issue: P0->A0(t+1)[t>=1], P1->B0(t+1)[t>=1], P2->A1(t+1), P3->B1(t+1)
//      guard: end-P1 VMW(4) covers A1,B1(t) (VMW(0) at t=nt-1);
//             end-P3 VMW(4) covers A0,B0(t+1) (skip at t=nt-1)
//      prologue: A0B0A1B1(0)+A0B0(1)=12 loads; VMW(8) covers A0,B0(0)
//  - epilogue: acc -> LDS stripes [32][264] -> full-line coalesced stores
//    (kills the write amplification; Vpt columns get full 64B lines)
// Kernels: prep (unchanged) -> proj8 (384 blk) -> scores8 (256) -> pv8 (128)
// Workspace layout unchanged (86.2 MB high-water).

using short8  = __attribute__((ext_vector_type(8))) short;
using floatx4 = __attribute__((ext_vector_type(4))) float;

// round-half-up bf16 (2 VALU; differs from RNE only on exact ties)
__device__ __forceinline__ unsigned short f2bf(float f) {
    union { float f; unsigned u; } x; x.f = f;
    return (unsigned short)((x.u + 0x8000u) >> 16);
}

__device__ __forceinline__ void gload_lds16(const unsigned short* g, unsigned short* l) {
    __builtin_amdgcn_global_load_lds(
        (const __attribute__((address_space(1))) unsigned int*)g,
        (__attribute__((address_space(3))) unsigned int*)l, 16, 0, 0);
}

#define SBAR    __builtin_amdgcn_s_barrier()
#define SCHEDB  __builtin_amdgcn_sched_barrier(0)
#define PRIO1   __builtin_amdgcn_s_setprio(1)
#define PRIO0   __builtin_amdgcn_s_setprio(0)
#define LGKM(n) asm volatile("s_waitcnt lgkmcnt(" #n ")" ::: "memory")
#define VMW(n)  asm volatile("s_waitcnt vmcnt(" #n ")" ::: "memory")

// ---------------- prep: qkv conv (blocks 0..24575) + W transpose (24576..27647) ----
__global__ __launch_bounds__(256) void prep(
    const float* __restrict__ q, const float* __restrict__ k, const float* __restrict__ v,
    const float* __restrict__ W0, const float* __restrict__ W1, const float* __restrict__ W2,
    unsigned short* __restrict__ qkvbf, unsigned short* __restrict__ Wt)
{
    __shared__ float tile[32][33];
    const int id = blockIdx.x;
    const int t  = threadIdx.x;
    if (id < 24576) {
        const int z  = id >> 13;
        const int xb = id & 8191;
        const float* x = (z == 0) ? q : (z == 1) ? k : v;
        const size_t i = ((size_t)xb * 256 + t) * 4;
        const float4 a = *(const float4*)(x + i);
        ushort4 p = { f2bf(a.x), f2bf(a.y), f2bf(a.z), f2bf(a.w) };
        *(ushort4*)(qkvbf + (size_t)z * 8192 * 1024 + i) = p;
    } else {
        const int idt = id - 24576;
        const int z  = idt >> 10;
        const int r  = idt & 1023;
        const int bx = (r & 31) * 32;
        const int by = (r >> 5) * 32;
        const float* W = (z == 0) ? W0 : (z == 1) ? W1 : W2;
        unsigned short* o = Wt + (size_t)z * 1024 * 1024;
        const int tx = t & 31;
        const int ty = (t >> 5) * 4;
        #pragma unroll
        for (int rr = 0; rr < 4; ++rr)
            tile[ty + rr][tx] = W[(size_t)(by + ty + rr) * 1024 + bx + tx];
        __syncthreads();
        #pragma unroll
        for (int rr = 0; rr < 4; ++rr)
            o[(size_t)(bx + ty + rr) * 1024 + by + tx] = f2bf(tile[tx][ty + rr]);
    }
}

// ======== 256x256 4-phase GEMM (bf16, K multiple of 64) ========
// LDS (shorts): buf b at b*32768; A-kh at kh*8192, B-kh at 16384+kh*8192;
// each region [256 rows][32 cols]. Swizzle: 16B slot s of row r holds
// global slot s ^ ((r>>1)&3).

#define STAGE_A(bb, kh, tt) do { \
    const unsigned short* s_ = gA + (size_t)srowA * lda + (tt) * 64 + (kh) * 32 + scol; \
    unsigned short* d_ = lds + (bb) * 32768 + (kh) * 8192 + t512 * 8; \
    gload_lds16(s_, d_); \
    gload_lds16(s_ + (size_t)128 * lda, d_ + 4096); \
} while (0)

#define STAGE_B(bb, kh, tt) do { \
    const unsigned short* s_ = gB + (size_t)srowA * ldb + (tt) * 64 + (kh) * 32 + scol; \
    unsigned short* d_ = lds + (bb) * 32768 + 16384 + (kh) * 8192 + t512 * 8; \
    gload_lds16(s_, d_); \
    gload_lds16(s_ + (size_t)128 * ldb, d_ + 4096); \
} while (0)

#define LDSA(bb, kh, i) (*(const short8*)&lds[(bb) * 32768 + (kh) * 8192 + (arow + (i) * 16) * 32 + rslot])
#define LDSB(bb, kh, j) (*(const short8*)&lds[(bb) * 32768 + 16384 + (kh) * 8192 + (brow + (j) * 16) * 32 + rslot])

#define MM4x4(IB) do { \
    PRIO1; \
    _Pragma("unroll") \
    for (int i_ = 0; i_ < 4; ++i_) \
        _Pragma("unroll") \
        for (int j_ = 0; j_ < 4; ++j_) \
            acc[(IB) + i_][j_] = __builtin_amdgcn_mfma_f32_16x16x32_bf16( \
                af[i_], bf[j_], acc[(IB) + i_][j_], 0, 0, 0); \
    PRIO0; \
} while (0)

__device__ __forceinline__ void gemm256(
    const unsigned short* __restrict__ gA, int lda,
    const unsigned short* __restrict__ gB, int ldb,
    int nt, unsigned short* lds, floatx4 (&acc)[8][4])
{
    const int t512 = threadIdx.x;
    const int lane = t512 & 63;
    const int wave = t512 >> 6;
    const int wr   = wave >> 2;          // 0..1 (M half)
    const int wc   = wave & 3;           // 0..3 (N quarter)
    const int l15  = lane & 15;
    const int quad = lane >> 4;
    const int srowA = t512 >> 2;                                 // staging row 0..127
    const int scol  = ((t512 & 3) ^ ((t512 >> 3) & 3)) * 8;      // pre-swizzled global slot
    const int rslot = (quad ^ ((l15 >> 1) & 3)) * 8;             // swizzled read slot
    const int arow  = wr * 128 + l15;
    const int brow  = wc * 64 + l15;

    short8 af[4], bf[4];

    // prologue: tile0 {A0,B0,A1,B1} + tile1 {A0,B0} = 12 loads
    STAGE_A(0, 0, 0); STAGE_B(0, 0, 0);
    STAGE_A(0, 1, 0); STAGE_B(0, 1, 0);
    STAGE_A(1, 0, 1); STAGE_B(1, 0, 1);
    VMW(8);            // A0(0), B0(0) landed
    SBAR;

    int p = 0;
    for (int t = 0; t < nt; ++t, p ^= 1) {
        // ---- P0: quadrant i0..3, k-half 0 ----
        #pragma unroll
        for (int j = 0; j < 4; ++j) bf[j] = LDSB(p, 0, j);
        #pragma unroll
        for (int i = 0; i < 4; ++i) af[i] = LDSA(p, 0, i);
        if (t >= 1 && t + 1 < nt) STAGE_A(p ^ 1, 0, t + 1);
        SBAR; LGKM(0); SCHEDB;
        MM4x4(0);
        SBAR;
        // ---- P1: quadrant i4..7, k-half 0 (bf reused) ----
        #pragma unroll
        for (int i = 0; i < 4; ++i) af[i] = LDSA(p, 0, i + 4);
        if (t >= 1 && t + 1 < nt) STAGE_B(p ^ 1, 0, t + 1);
        SBAR; LGKM(0); SCHEDB;
        MM4x4(4);
        if (t + 1 < nt) { VMW(4); } else { VMW(0); }   // A1,B1(t) landed
        SBAR;
        // ---- P2: quadrant i0..3, k-half 1 ----
        #pragma unroll
        for (int j = 0; j < 4; ++j) bf[j] = LDSB(p, 1, j);
        #pragma unroll
        for (int i = 0; i < 4; ++i) af[i] = LDSA(p, 1, i);
        if (t + 1 < nt) STAGE_A(p ^ 1, 1, t + 1);
        SBAR; LGKM(0); SCHEDB;
        MM4x4(0);
        SBAR;
        // ---- P3: quadrant i4..7, k-half 1 (bf reused) ----
        #pragma unroll
        for (int i = 0; i < 4; ++i) af[i] = LDSA(p, 1, i + 4);
        if (t + 1 < nt) STAGE_B(p ^ 1, 1, t + 1);
        SBAR; LGKM(0); SCHEDB;
        MM4x4(4);
        if (t + 1 < nt) { VMW(4); }                    // A0,B0(t+1) landed
        SBAR;
    }
}

#define EPI_IDS                                   \
    const int tt   = threadIdx.x;                 \
    const int lane = tt & 63;                     \
    const int wave = tt >> 6;                     \
    const int wr   = wave >> 2;                   \
    const int wc   = wave & 3;                    \
    const int l15  = lane & 15;                   \
    const int quad = lane >> 4;

// ---------------- fused QKV projection, 384 blocks, XCD-swizzled ----
__global__ __launch_bounds__(512) void proj8(
    const unsigned short* __restrict__ Abf,
    const unsigned short* __restrict__ Wt,
    const float* __restrict__ bq, const float* __restrict__ bk, const float* __restrict__ bv,
    unsigned short* __restrict__ Qp, unsigned short* __restrict__ Kp,
    unsigned short* __restrict__ Vpt)
{
    __shared__ __attribute__((aligned(16))) unsigned short lds[65536];
    const int id = blockIdx.x;
    const int g  = (id & 7) * 48 + (id >> 3);    // 384 = 8 XCDs x 48
    const int z  = g >> 7;                       // 0..2
    const int r  = g & 127;
    const int m0 = (r >> 2) * 256;
    const int n0 = (r & 3) * 256;

    const unsigned short* gA = Abf + (size_t)z * 8192 * 1024 + (size_t)m0 * 1024;
    const unsigned short* gB = Wt  + (size_t)z * 1024 * 1024 + (size_t)n0 * 1024;

    floatx4 acc[8][4] = {};
    gemm256(gA, 1024, gB, 1024, 16, lds, acc);

    EPI_IDS
    const float* bias = (z == 0) ? bq : (z == 1) ? bk : bv;
    float bvj[4];
    #pragma unroll
    for (int j = 0; j < 4; ++j) bvj[j] = bias[n0 + wc * 64 + j * 16 + l15];

    unsigned short (*sst)[264] = (unsigned short (*)[264])lds;
    for (int s = 0; s < 8; ++s) {
        if (wr == (s >> 2)) {
            const int i0 = (s & 3) * 2;
            #pragma unroll
            for (int ii = 0; ii < 2; ++ii)
                #pragma unroll
                for (int j = 0; j < 4; ++j)
                    #pragma unroll
                    for (int r2 = 0; r2 < 4; ++r2)
                        sst[ii * 16 + quad * 4 + r2][wc * 64 + j * 16 + l15] =
                            f2bf(acc[i0 + ii][j][r2] + bvj[j]);
        }
        SBAR;
        if (z < 2) {
            unsigned short* C = (z == 0) ? Qp : Kp;
            #pragma unroll
            for (int c = 0; c < 4; ++c) {
                const int a = c * 512 + tt, lr = a >> 6, cc = a & 63;
                *(ushort4*)(C + (size_t)(m0 + s * 32 + lr) * 1024 + n0 + cc * 4) =
                    *(const ushort4*)&sst[lr][cc * 4];
            }
        } else {
            #pragma unroll
            for (int c = 0; c < 4; ++c) {
                const int a = c * 512 + tt, col = a >> 3, ch = a & 7;
                ushort4 pk = { sst[ch * 4 + 0][col], sst[ch * 4 + 1][col],
                               sst[ch * 4 + 2][col], sst[ch * 4 + 3][col] };
                *(ushort4*)(Vpt + (size_t)(n0 + col) * 8192 + m0 + s * 32 + ch * 4) = pk;
            }
        }
        SBAR;
    }
}

// ---------------- scores: Pexp = exp(Qp @ Kp^T / 32) bf16 + row sums ----
__global__ __launch_bounds__(512) void scores8(
    const unsigned short* __restrict__ Qp,
    const unsigned short* __restrict__ Kp,
    unsigned short* __restrict__ Pexp,
    float* __restrict__ rowsum)
{
    __shared__ __attribute__((aligned(16))) unsigned short lds[65536];
    const int id = blockIdx.x;
    const int g  = (id & 7) * 32 + (id >> 3);    // 256 blocks
    const int z  = g >> 6;
    const int r  = g & 63;
    const int m0 = (r >> 3) * 256;
    const int n0 = (r & 7) * 256;

    const unsigned short* gA = Qp + (size_t)z * 2048 * 1024 + (size_t)m0 * 1024;
    const unsigned short* gB = Kp + (size_t)z * 2048 * 1024 + (size_t)n0 * 1024;

    floatx4 acc[8][4] = {};
    gemm256(gA, 1024, gB, 1024, 16, lds, acc);

    EPI_IDS
    unsigned short* P = Pexp + (size_t)z * 2048 * 2048;
    float* rs = rowsum + (size_t)z * 2048;

    // transform acc -> p = exp(s/32); then row-sum reduce + atomics
    #pragma unroll
    for (int i = 0; i < 8; ++i) {
        const int rowb = m0 + wr * 128 + i * 16 + quad * 4;
        float sm[4] = {0.f, 0.f, 0.f, 0.f};
        #pragma unroll
        for (int j = 0; j < 4; ++j)
            #pragma unroll
            for (int r2 = 0; r2 < 4; ++r2) {
                const float pv_ = __expf(acc[i][j][r2] * 0.03125f);
                acc[i][j][r2] = pv_;
                sm[r2] += pv_;
            }
        #pragma unroll
        for (int r2 = 0; r2 < 4; ++r2) {
            float sv = sm[r2];
            sv += __shfl_xor(sv, 1);
            sv += __shfl_xor(sv, 2);
            sv += __shfl_xor(sv, 4);
            sv += __shfl_xor(sv, 8);
            if (l15 == 0)
                atomicAdd(&rs[rowb + r2], sv);
        }
    }

    unsigned short (*sst)[264] = (unsigned short (*)[264])lds;
    for (int s = 0; s < 8; ++s) {
        if (wr == (s >> 2)) {
            const int i0 = (s & 3) * 2;
            #pragma unroll
            for (int ii = 0; ii < 2; ++ii)
                #pragma unroll
                for (int j = 0; j < 4; ++j)
                    #pragma unroll
                    for (int r2 = 0; r2 < 4; ++r2)
                        sst[ii * 16 + quad * 4 + r2][wc * 64 + j * 16 + l15] =
                            f2bf(acc[i0 + ii][j][r2]);
        }
        SBAR;
        #pragma unroll
        for (int c = 0; c < 4; ++c) {
            const int a = c * 512 + tt, lr = a >> 6, cc = a & 63;
            *(ushort4*)(P + (size_t)(m0 + s * 32 + lr) * 2048 + n0 + cc * 4) =
                *(const ushort4*)&sst[lr][cc * 4];
        }
        SBAR;
    }
}

// ---------------- PV: out = (Pexp @ Vpt^T) / rowsum, fp32 ----------------
__global__ __launch_bounds__(512) void pv8(
    const unsigned short* __restrict__ Pexp,
    const unsigned short* __restrict__ Vpt,
    const float* __restrict__ rowsum,
    float* __restrict__ out)
{
    __shared__ __attribute__((aligned(16))) unsigned short lds[65536];
    const int id = blockIdx.x;
    const int g  = (id & 7) * 16 + (id >> 3);    // 128 blocks
    const int z  = g >> 5;
    const int r  = g & 31;
    const int m0 = (r >> 2) * 256;
    const int n0 = (r & 3) * 256;

    const unsigned short* gA = Pexp + (size_t)z * 2048 * 2048 + (size_t)m0 * 2048;
    const unsigned short* gB = Vpt  + (size_t)n0 * 8192 + (size_t)z * 2048;

    floatx4 acc[8][4] = {};
    gemm256(gA, 2048, gB, 8192, 32, lds, acc);

    EPI_IDS
    const float* rs = rowsum + (size_t)z * 2048;
    float* C = out + (size_t)z * 2048 * 1024;

    float (*sstF)[264] = (float (*)[264])lds;
    for (int s = 0; s < 8; ++s) {
        if (wr == (s >> 2)) {
            const int i0 = (s & 3) * 2;
            #pragma unroll
            for (int ii = 0; ii < 2; ++ii) {
                const int rowb = m0 + wr * 128 + (i0 + ii) * 16 + quad * 4;
                float inv[4];
                #pragma unroll
                for (int r2 = 0; r2 < 4; ++r2) inv[r2] = 1.0f / rs[rowb + r2];
                #pragma unroll
                for (int j = 0; j < 4; ++j)
                    #pragma unroll
                    for (int r2 = 0; r2 < 4; ++r2)
                        sstF[ii * 16 + quad * 4 + r2][wc * 64 + j * 16 + l15] =
                            acc[i0 + ii][j][r2] * inv[r2];
            }
        }
        SBAR;
        #pragma unroll
        for (int c = 0; c < 4; ++c) {
            const int a = c * 512 + tt, lr = a >> 6, cc = a & 63;
            *(float4*)(C + (size_t)(m0 + s * 32 + lr) * 1024 + n0 + cc * 4) =
                *(const float4*)&sstF[lr][cc * 4];
        }
        SBAR;
    }
}

extern "C" void kernel_launch(void* const* d_in, const int* in_sizes, int n_in,
                              void* d_out, int out_size, void* d_ws, size_t ws_size,
                              hipStream_t stream)
{
    const float* q  = (const float*)d_in[0];
    const float* k  = (const float*)d_in[1];
    const float* v  = (const float*)d_in[2];
    const float* Wq = (const float*)d_in[3];
    const float* bq = (const float*)d_in[4];
    const float* Wk = (const float*)d_in[5];
    const float* bk = (const float*)d_in[6];
    const float* Wv = (const float*)d_in[7];
    const float* bv = (const float*)d_in[8];
    float* out = (float*)d_out;

    const int Bn = 4, S = 2048;

    char* w = (char*)d_ws;
    unsigned short* Wt     = (unsigned short*)(w);                  // 6 MB
    unsigned short* Qp     = (unsigned short*)(w + (6u << 20));     // 16 MB [8192,1024]
    unsigned short* Kp     = (unsigned short*)(w + (22u << 20));    // 16 MB
    unsigned short* Vpt    = (unsigned short*)(w + (38u << 20));    // 16 MB [1024,8192]
    unsigned short* qkvbf  = (unsigned short*)(w + (54u << 20));    // 48 MB (dead after proj)
    unsigned short* Pexp   = (unsigned short*)(w + (54u << 20));    // 32 MB (over dead qkvbf)
    float*          rowsum = (float*)(w + (86u << 20));             // 32 KB

    // zero the row-sum accumulators (ws is poisoned before each call)
    hipMemsetAsync(rowsum, 0, (size_t)Bn * S * sizeof(float), stream);

    // prep: qkv fp32->bf16 + W->W^T bf16
    prep<<<dim3(27648), dim3(256), 0, stream>>>(q, k, v, Wq, Wk, Wv, qkvbf, Wt);

    // fused projections (256^2 4-phase): -> Qp, Kp, Vpt^T
    proj8<<<dim3(384), dim3(512), 0, stream>>>(qkvbf, Wt, bq, bk, bv, Qp, Kp, Vpt);

    // Pexp = exp(Qp @ Kp^T / 32) bf16 + rowsum atomics
    scores8<<<dim3(256), dim3(512), 0, stream>>>(Qp, Kp, Pexp, rowsum);

    // out = (Pexp @ Vpt^T) / rowsum
    pv8<<<dim3(128), dim3(512), 0, stream>>>(Pexp, Vpt, rowsum, out);
}